// Round 8
// baseline (110.776 us; speedup 1.0000x reference)
//
#include <hip/hip_runtime.h>
#include <hip/hip_bf16.h>

#define B_    8
#define S_    4096
#define DIN   512
#define DOUT  64
#define NROWS (B_ * S_)   // 32768

typedef __attribute__((ext_vector_type(8))) short bf16x8;
typedef __attribute__((ext_vector_type(4))) float f32x4;
typedef __attribute__((ext_vector_type(2))) unsigned int u32x2;
typedef __attribute__((ext_vector_type(2))) int i32x2;

typedef const __attribute__((address_space(1))) unsigned int GUI;
typedef __attribute__((address_space(3))) unsigned int LUI;

__device__ __forceinline__ unsigned short f32_to_bf16(float f) {
    union { float f; unsigned int u; } c; c.f = f;
    unsigned int r = (c.u + 0x7FFFu + ((c.u >> 16) & 1u)) >> 16;
    return (unsigned short)r;
}

__device__ __forceinline__ float fast_exp2(float x) {
#if __has_builtin(__builtin_amdgcn_exp2f)
    return __builtin_amdgcn_exp2f(x);    // single v_exp_f32 (D = 2^S0)
#else
    return exp2f(x);
#endif
}

// Combined-with-partner (lane^32) reductions via v_permlane32_swap.
// swap(v,v) returns {[v_lo|v_lo], [v_hi|v_hi]}: at every lane the two words
// are {v[lane], v[lane^32]} in some order -> combine BOTH (order-agnostic).
__device__ __forceinline__ float max_xor32(float v) {
#if __has_builtin(__builtin_amdgcn_permlane32_swap)
    i32x2 r = __builtin_amdgcn_permlane32_swap(__float_as_int(v), __float_as_int(v),
                                               false, false);
    return fmaxf(__int_as_float(r.x), __int_as_float(r.y));
#else
    return fmaxf(v, __shfl_xor(v, 32, 64));
#endif
}
__device__ __forceinline__ float sum_xor32(float v) {
#if __has_builtin(__builtin_amdgcn_permlane32_swap)
    i32x2 r = __builtin_amdgcn_permlane32_swap(__float_as_int(v), __float_as_int(v),
                                               false, false);
    return __int_as_float(r.x) + __int_as_float(r.y);
#else
    return v + __shfl_xor(v, 32, 64);
#endif
}

// Rule-18 fence: all outstanding LDS ops of this wave COMPLETE here (see r6).
#define LDS_READS_DONE_FENCE() do {                                   \
    asm volatile("s_waitcnt lgkmcnt(0)" ::: "memory");                \
    __builtin_amdgcn_sched_barrier(0);                                \
} while (0)

// partial-chunk index for j>=1 (t>=16); 96 entries per batch
__device__ __forceinline__ int pidx_of(int t, int j) {
    if (t < 32) return (t - 16);                    // j==1 only
    if (t < 48) return 16 + (t - 32) * 2 + (j - 1); // j in {1,2}
    return 48 + (t - 48) * 3 + (j - 1);             // j in {1,2,3}
}

// ---------------------------------------------------------------------------
// Kernel 1: W_Q|W_K|W_V ([512][64] f32 each) -> Wt2 bf16 in B-frag order:
// Wt2[ks][nf][c15][kl], ks=k>>5, nf=p*4+(n>>4), c15=n&15, kl=k&31.
// ---------------------------------------------------------------------------
__global__ void wt_convert(const float* __restrict__ WQ,
                           const float* __restrict__ WK,
                           const float* __restrict__ WV,
                           unsigned short* __restrict__ Wt2) {
    int idx = blockIdx.x * 256 + threadIdx.x;
    if (idx >= 3 * 512 * 16) return;
    int p   = idx / 8192;
    int rem = idx - p * 8192;
    int k   = rem >> 4;
    int n0  = (rem & 15) * 4;
    const float* W = (p == 0) ? WQ : ((p == 1) ? WK : WV);
    float4 v = *(const float4*)(W + k * 64 + n0);
    const int ks = k >> 5, kl = k & 31;
    float vv[4] = {v.x, v.y, v.z, v.w};
#pragma unroll
    for (int r = 0; r < 4; ++r) {
        int n = n0 + r;
        Wt2[(size_t)((ks * 12 + p * 4 + (n >> 4)) * 512) + (n & 15) * 32 + kl] =
            f32_to_bf16(vv[r]);
    }
}

// ---------------------------------------------------------------------------
// Kernel 2: fused QKV projection (unchanged from round 6 — proven correct).
// ---------------------------------------------------------------------------
__global__ __launch_bounds__(256) void qkv_proj(const float* __restrict__ x,
                                                const unsigned short* __restrict__ Wt2,
                                                unsigned short* __restrict__ QKV) {
    __shared__ alignas(16) float          xtile[2][1024];  // [32 rows][8 slots], swz
    __shared__ alignas(16) unsigned short btile[2][6144];  // [nf][c15][kl] linear

    const int tid  = threadIdx.x;
    const int lane = tid & 63;
    const int wq   = tid >> 6;
    const int c15  = lane & 15;
    const int g    = lane >> 4;
    const float* xblk = x + (size_t)blockIdx.x * 32 * DIN;

    const int rw     = (wq & 1) * 16 + c15;
    const int nfbase = (wq >> 1) * 6;

    const int xrow = wq * 8 + (lane >> 3);
    const int xsl  = (lane & 7) ^ (xrow & 7);

    auto stage = [&](int slot, int ks) {
        __builtin_amdgcn_global_load_lds((GUI*)(xblk + ks * 32 + xrow * DIN + xsl * 4),
                                         (LUI*)((char*)&xtile[slot][0] + wq * 1024), 16, 0, 0);
        const unsigned short* Bs = Wt2 + (size_t)ks * 6144;
#pragma unroll
        for (int j = 0; j < 3; ++j)
            __builtin_amdgcn_global_load_lds((GUI*)(Bs + (j * 256 + tid) * 8),
                                             (LUI*)((char*)&btile[slot][0] + j * 4096 + wq * 1024),
                                             16, 0, 0);
    };
    stage(0, 0);
    stage(1, 1);

    f32x4 acc[6] = {};

    int cur = 0;
    for (int ks = 0; ks < 16; ++ks) {
        asm volatile("s_waitcnt vmcnt(4)" ::: "memory");
        asm volatile("s_barrier" ::: "memory");

        const char* xb = (const char*)&xtile[cur][0] + rw * 128;
        f32x4 a0 = *(const f32x4*)(xb + (((2 * g)     ^ (rw & 7)) << 4));
        f32x4 a1 = *(const f32x4*)(xb + (((2 * g + 1) ^ (rw & 7)) << 4));
        union { unsigned w[4]; bf16x8 v; } af;
        asm("v_cvt_pk_bf16_f32 %0, %1, %2" : "=v"(af.w[0]) : "v"(a0[0]), "v"(a0[1]));
        asm("v_cvt_pk_bf16_f32 %0, %1, %2" : "=v"(af.w[1]) : "v"(a0[2]), "v"(a0[3]));
        asm("v_cvt_pk_bf16_f32 %0, %1, %2" : "=v"(af.w[2]) : "v"(a1[0]), "v"(a1[1]));
        asm("v_cvt_pk_bf16_f32 %0, %1, %2" : "=v"(af.w[3]) : "v"(a1[2]), "v"(a1[3]));

        const char* bb = (const char*)&btile[cur][0] + c15 * 64 + g * 16;
#pragma unroll
        for (int n = 0; n < 6; ++n) {
            bf16x8 bf = *(const bf16x8*)(bb + (nfbase + n) * 1024);
            acc[n] = __builtin_amdgcn_mfma_f32_16x16x32_bf16(af.v, bf, acc[n], 0, 0, 0);
        }

        LDS_READS_DONE_FENCE();
        asm volatile("s_barrier" ::: "memory");
        {
            int tn = ks + 2; if (tn > 15) tn = 15;
            stage(cur, tn);
        }
        cur ^= 1;
    }
    asm volatile("s_waitcnt vmcnt(0)" ::: "memory");

    const int orow0 = blockIdx.x * 32 + (wq & 1) * 16 + g * 4;
#pragma unroll
    for (int n = 0; n < 6; ++n) {
        const int nfg  = nfbase + n;
        const int p    = nfg >> 2;
        const int ncol = (nfg & 3) * 16 + c15;
        if (p < 2) {
            unsigned short* outp = QKV + (size_t)p * NROWS * DOUT;
            const float sc = (p == 0) ? 0.125f * 1.44269504089f : 1.0f;
#pragma unroll
            for (int r = 0; r < 4; ++r)
                outp[(size_t)(orow0 + r) * DOUT + ncol] = f32_to_bf16(acc[n][r] * sc);
        } else {
            const int bb2  = orow0 >> 12;
            const int srow = orow0 & 4095;
            union { unsigned short s[4]; u32x2 d; } pk;
#pragma unroll
            for (int r = 0; r < 4; ++r) pk.s[r] = f32_to_bf16(acc[n][r]);
            *(u32x2*)(QKV + (size_t)2 * NROWS * DOUT +
                      ((size_t)bb2 * DOUT + ncol) * S_ + srow) = pk.d;
        }
    }
}

// ---------------------------------------------------------------------------
// Kernel 3: causal flash attention, S^T/O^T, chunked split-KV (C=16 tiles).
// Grid 1280 = 8 batches x 160 chunks. Max serial chain = 16 KV-tiles.
// ---------------------------------------------------------------------------
__global__ __launch_bounds__(256) void attn_fwd(const unsigned short* __restrict__ QKV,
                                                float* __restrict__ out,
                                                char* __restrict__ part1,
                                                float* __restrict__ ml0) {
    __shared__ alignas(16) unsigned short k_lds[2][4096];
    __shared__ alignas(16) unsigned short v_lds[2][4096];
    __shared__ alignas(16) unsigned short p_lds[4][1024];

    const int bid = blockIdx.x;
    const int b   = bid & 7;
    const int i   = bid >> 3;             // 0..159
    int j, t;
    if      (i < 64)  { j = 0; t = i; }
    else if (i < 112) { j = 1; t = 16 + (i - 64); }
    else if (i < 144) { j = 2; t = 32 + (i - 112); }
    else              { j = 3; t = 48 + (i - 144); }
    const int tile_lo  = j * 16;
    const int tile_hi  = min(tile_lo + 15, t);
    const int tile_cnt = tile_hi - tile_lo + 1;
    const bool do_diag = (tile_hi == t);
    const int q0 = t * 64;

    const int tid  = threadIdx.x;
    const int lane = tid & 63;
    const int wq   = tid >> 6;
    const int c15  = lane & 15;
    const int g    = lane >> 4;

    const unsigned short* Qg  = QKV + (size_t)b * S_ * DOUT;
    const unsigned short* Kg  = QKV + (size_t)NROWS * DOUT + (size_t)b * S_ * DOUT;
    const unsigned short* VTg = QKV + (size_t)2 * NROWS * DOUT + (size_t)b * DOUT * S_;

    const size_t qoff = (size_t)(q0 + wq * 16 + c15) * DOUT;
    bf16x8 qf0 = *(const bf16x8*)(Qg + qoff + g * 8);
    bf16x8 qf1 = *(const bf16x8*)(Qg + qoff + 32 + g * 8);
    asm volatile("s_waitcnt vmcnt(0)" ::: "memory");  // exact vmcnt bookkeeping

    const int i0 = wq * 128 + lane;
    const int i1 = i0 + 64;
    const int r0 = i0 >> 3, s0 = (i0 & 7) ^ (r0 & 7);
    const int r1 = i1 >> 3, s1 = (i1 & 7) ^ (r1 & 7);

    auto stage = [&](int slot, int tg) {
        const unsigned short* Kt = Kg + (size_t)tg * 64 * DOUT;
        const unsigned short* Vt = VTg + tg * 64;
        char* kbase = (char*)&k_lds[slot][0] + wq * 2048;
        char* vbase = (char*)&v_lds[slot][0] + wq * 2048;
        __builtin_amdgcn_global_load_lds((GUI*)(Kt + r0 * DOUT + s0 * 8), (LUI*)kbase, 16, 0, 0);
        __builtin_amdgcn_global_load_lds((GUI*)(Kt + r1 * DOUT + s1 * 8), (LUI*)(kbase + 1024), 16, 0, 0);
        __builtin_amdgcn_global_load_lds((GUI*)(Vt + (size_t)r0 * S_ + s0 * 8), (LUI*)vbase, 16, 0, 0);
        __builtin_amdgcn_global_load_lds((GUI*)(Vt + (size_t)r1 * S_ + s1 * 8), (LUI*)(vbase + 1024), 16, 0, 0);
    };

    stage(0, tile_lo);
    stage(1, tile_lo + (tile_cnt > 1 ? 1 : 0));

    f32x4 oacc[4] = {};
    float m_r = -3.0e38f, l_r = 0.f;

    int cur = 0;
    for (int itl = 0; itl < tile_cnt; ++itl) {
        const int tg = tile_lo + itl;
        asm volatile("s_waitcnt vmcnt(4)" ::: "memory");
        asm volatile("s_barrier" ::: "memory");

        const char* kb = (const char*)&k_lds[cur][0];
        const char* vb = (const char*)&v_lds[cur][0];

        // --- S^T = mfma(K, Q): lane holds S^T[kv = 16nf+4g+r][q = c15] ---
        f32x4 s[4];
#pragma unroll
        for (int nf = 0; nf < 4; ++nf) {
            const char* krow = kb + (nf * 16 + c15) * 128;
            bf16x8 kf0 = *(const bf16x8*)(krow + ((g ^ (c15 & 7)) << 4));
            bf16x8 kf1 = *(const bf16x8*)(krow + (((4 + g) ^ (c15 & 7)) << 4));
            f32x4 z = {};
            z = __builtin_amdgcn_mfma_f32_16x16x32_bf16(kf0, qf0, z, 0, 0, 0);
            z = __builtin_amdgcn_mfma_f32_16x16x32_bf16(kf1, qf1, z, 0, 0, 0);
            s[nf] = z;
        }

        if (do_diag && tg == t) {
            const int ql = wq * 16 + c15;
#pragma unroll
            for (int nf = 0; nf < 4; ++nf)
#pragma unroll
                for (int r = 0; r < 4; ++r)
                    if (16 * nf + 4 * g + r > ql) s[nf][r] = -1.0e30f;
        }

        // --- lane-local online softmax in exp2 domain (q = c15) ---
        float mx = s[0][0];
#pragma unroll
        for (int nf = 0; nf < 4; ++nf)
#pragma unroll
            for (int r = 0; r < 4; ++r) mx = fmaxf(mx, s[nf][r]);
        mx = max_xor32(mx);
        mx = fmaxf(mx, __shfl_xor(mx, 16, 64));
        const float mnew = fmaxf(m_r, mx);
        const float alpha = fast_exp2(m_r - mnew);
        m_r = mnew;

        float p[4][4];
        float sum = 0.f;
#pragma unroll
        for (int nf = 0; nf < 4; ++nf)
#pragma unroll
            for (int r = 0; r < 4; ++r) {
                p[nf][r] = fast_exp2(s[nf][r] - mnew);
                sum += p[nf][r];
            }
        sum = sum_xor32(sum);
        sum += __shfl_xor(sum, 16, 64);
        l_r = l_r * alpha + sum;
#pragma unroll
        for (int df = 0; df < 4; ++df)
#pragma unroll
            for (int r = 0; r < 4; ++r) oacc[df][r] *= alpha;

        // --- P^T -> bf16 pairs into per-wave swizzled LDS (w = kv/2) ---
#pragma unroll
        for (int nf = 0; nf < 4; ++nf)
#pragma unroll
            for (int pr = 0; pr < 2; ++pr) {
                unsigned pw;
                asm("v_cvt_pk_bf16_f32 %0, %1, %2"
                    : "=v"(pw) : "v"(p[nf][2 * pr]), "v"(p[nf][2 * pr + 1]));
                const int w = 8 * nf + 2 * g + pr;
                *(unsigned*)((char*)&p_lds[wq][0] + c15 * 128 +
                             (((w >> 2) ^ (c15 & 7)) << 4) + (w & 3) * 4) = pw;
            }

        bf16x8 pf[2];
#pragma unroll
        for (int kk = 0; kk < 2; ++kk)
            pf[kk] = *(const bf16x8*)((char*)&p_lds[wq][0] + c15 * 128 +
                                      (((4 * kk + g) ^ (c15 & 7)) << 4));

        // --- O^T += mfma(V^T, P^T): lane holds O^T[d = 16df+4g+r][q = c15] ---
#pragma unroll
        for (int df = 0; df < 4; ++df) {
            const char* vrow = vb + (df * 16 + c15) * 128;
            bf16x8 vf0 = *(const bf16x8*)(vrow + ((g ^ (c15 & 7)) << 4));
            bf16x8 vf1 = *(const bf16x8*)(vrow + (((4 + g) ^ (c15 & 7)) << 4));
            oacc[df] = __builtin_amdgcn_mfma_f32_16x16x32_bf16(vf0, pf[0], oacc[df], 0, 0, 0);
            oacc[df] = __builtin_amdgcn_mfma_f32_16x16x32_bf16(vf1, pf[1], oacc[df], 0, 0, 0);
        }

        LDS_READS_DONE_FENCE();
        asm volatile("s_barrier" ::: "memory");
        {
            int tn = itl + 2; if (tn >= tile_cnt) tn = tile_cnt - 1;
            stage(cur, tile_lo + tn);
        }
        cur ^= 1;
    }

    asm volatile("s_waitcnt vmcnt(0)" ::: "memory");   // drain LDS-DMA pre-endpgm

    const int ql = wq * 16 + c15;
    if (t < 16) {
        // direct normalized write
        const float linv = 1.0f / l_r;
        float* outp = out + (size_t)b * S_ * DOUT + (size_t)(q0 + ql) * DOUT;
#pragma unroll
        for (int df = 0; df < 4; ++df)
#pragma unroll
            for (int r = 0; r < 4; ++r)
                outp[df * 16 + 4 * g + r] = oacc[df][r] * linv;
    } else if (j == 0) {
        // unnormalized f32 O in-place into the out tile + m/l to ml0
        float* outp = out + (size_t)b * S_ * DOUT + (size_t)(q0 + ql) * DOUT;
#pragma unroll
        for (int df = 0; df < 4; ++df)
#pragma unroll
            for (int r = 0; r < 4; ++r)
                outp[df * 16 + 4 * g + r] = oacc[df][r];
        if (g == 0) {
            float* ml = ml0 + (size_t)(b * 48 + (t - 16)) * 128;
            ml[ql] = m_r; ml[64 + ql] = l_r;
        }
    } else {
        // bf16 OT partial: [m f32[64] | l f32[64] | O bf16 [q][d] 64x64]
        char* pb = part1 + (size_t)(b * 96 + pidx_of(t, j)) * 8704;
        if (g == 0) {
            float* mf = (float*)pb;
            mf[ql] = m_r; mf[64 + ql] = l_r;
        }
        unsigned short* ob = (unsigned short*)(pb + 512);
#pragma unroll
        for (int df = 0; df < 4; ++df) {
            union { unsigned short s[4]; u32x2 d; } pk;
#pragma unroll
            for (int r = 0; r < 4; ++r) pk.s[r] = f32_to_bf16(oacc[df][r]);
            *(u32x2*)(ob + ql * 64 + df * 16 + 4 * g) = pk.d;
        }
    }
}

// ---------------------------------------------------------------------------
// Kernel 4: combine 2-4 KV-chunks for q-tiles t>=16 (chunk0 lives in-place
// in the out tile as unnormalized f32; chunks 1..nc-1 are bf16 in part1).
// Grid 384 = 8 batches x 48 tiles; 256 thr: d = tid&63, q stride 4.
// ---------------------------------------------------------------------------
__global__ __launch_bounds__(256) void attn_reduce(float* __restrict__ out,
                                                   const char* __restrict__ part1,
                                                   const float* __restrict__ ml0) {
    const int b  = blockIdx.x / 48;
    const int tz = blockIdx.x % 48;
    const int t  = tz + 16;
    const int nc = (t < 32) ? 2 : ((t < 48) ? 3 : 4);

    float* otile = out + ((size_t)b * S_ + (size_t)t * 64) * 64;
    const float* ml = ml0 + (size_t)(b * 48 + tz) * 128;
    const char* pbs[3];
    for (int jj = 1; jj < nc; ++jj)
        pbs[jj - 1] = part1 + (size_t)(b * 96 + pidx_of(t, jj)) * 8704;

    const int d  = threadIdx.x & 63;
    const int qb = threadIdx.x >> 6;

    for (int q = qb; q < 64; q += 4) {
        float m = ml[q], l = ml[64 + q];
        float M = m;
        float mj[3], lj[3];
        for (int jj = 0; jj < nc - 1; ++jj) {
            const float* mf = (const float*)pbs[jj];
            mj[jj] = mf[q]; lj[jj] = mf[64 + q];
            M = fmaxf(M, mj[jj]);
        }
        float e0 = fast_exp2(m - M);
        float L  = e0 * l;
        float O  = e0 * otile[q * 64 + d];
        for (int jj = 0; jj < nc - 1; ++jj) {
            float ej = fast_exp2(mj[jj] - M);
            L += ej * lj[jj];
            unsigned short us = ((const unsigned short*)(pbs[jj] + 512))[q * 64 + d];
            union { unsigned int u; float f; } cv; cv.u = (unsigned int)us << 16;
            O += ej * cv.f;
        }
        otile[q * 64 + d] = O / L;
    }
}

// ---------------------------------------------------------------------------
extern "C" void kernel_launch(void* const* d_in, const int* in_sizes, int n_in,
                              void* d_out, int out_size, void* d_ws, size_t ws_size,
                              hipStream_t stream) {
    const float* x  = (const float*)d_in[0];
    const float* WQ = (const float*)d_in[1];
    const float* WK = (const float*)d_in[2];
    const float* WV = (const float*)d_in[3];

    unsigned short* Wt2  = (unsigned short*)d_ws;              // 192 KB
    unsigned short* QKV  = Wt2 + 192 * 512;                    // 12 MB: Q | K | V^T
    char*           part1 = (char*)d_ws + 12779520;            // 768 x 8704 B = 6.37 MB
    float*          ml0   = (float*)((char*)d_ws + 19464192);  // 384 x 512 B

    wt_convert<<<96, 256, 0, stream>>>(WQ, WK, WV, Wt2);
    qkv_proj<<<1024, 256, 0, stream>>>(x, Wt2, QKV);
    attn_fwd<<<1280, 256, 0, stream>>>(QKV, (float*)d_out, part1, ml0);
    attn_reduce<<<384, 256, 0, stream>>>((float*)d_out, part1, ml0);
}